// Round 2
// baseline (891.404 us; speedup 1.0000x reference)
//
#include <hip/hip_runtime.h>
#include <hip/hip_bf16.h>

typedef __attribute__((ext_vector_type(8))) short short8;
typedef __attribute__((ext_vector_type(4))) float floatx4;

#define SCALE 0.17677669529663687f   // 32^-0.5
#define RSTR 136   // bf16 LDS row stride (elements)
#define QSTR 132   // q_s row stride (floats)

__device__ __forceinline__ unsigned f2bf_bits(float f) {
  union { float f; unsigned u; } v; v.f = f;
  unsigned u = v.u;
  return ((u + 0x7fffu + ((u >> 16) & 1u)) >> 16) & 0xffffu;  // RNE f32->bf16
}

__device__ __forceinline__ unsigned pack_bf2(float a, float b) {
  __hip_bfloat162 h = __float22bfloat162_rn(float2{a, b});   // v_cvt_pk_bf16_f32
  union { __hip_bfloat162 h; unsigned u; } cv; cv.h = h;
  return cv.u;   // low16 = a, high16 = b
}

// Fused LayerNorm + A-fragment build, registers only. Lane (l16,quad) owns row
// l16's cols [quad*8 + ks*32, +8). Row stats reduce across the 4 quads sharing
// the row (shfl_xor 16/32 only). ln_g/ln_b are folded into weights/bias, so
// normalization is just (v-mu)*inv.
__device__ __forceinline__ void ln_load_frag(const float* __restrict__ base,
                                             short8 af[4]) {
  float4 v[8];
#pragma unroll
  for (int ks = 0; ks < 4; ++ks) {
    v[2 * ks]     = *reinterpret_cast<const float4*>(base + ks * 32);
    v[2 * ks + 1] = *reinterpret_cast<const float4*>(base + ks * 32 + 4);
  }
  float s1 = 0.f, s2 = 0.f;
#pragma unroll
  for (int i = 0; i < 8; ++i) {
    s1 += (v[i].x + v[i].y) + (v[i].z + v[i].w);
    s2 = fmaf(v[i].x, v[i].x, s2); s2 = fmaf(v[i].y, v[i].y, s2);
    s2 = fmaf(v[i].z, v[i].z, s2); s2 = fmaf(v[i].w, v[i].w, s2);
  }
  s1 += __shfl_xor(s1, 16, 64); s1 += __shfl_xor(s1, 32, 64);
  s2 += __shfl_xor(s2, 16, 64); s2 += __shfl_xor(s2, 32, 64);
  float mu  = s1 * (1.0f / 128.0f);
  float var = fmaf(-mu, mu, s2 * (1.0f / 128.0f));
  float inv = rsqrtf(var + 1e-5f);
  float nmi = -mu * inv;
#pragma unroll
  for (int ks = 0; ks < 4; ++ks) {
    union { short8 s; unsigned u[4]; } cv;
    cv.u[0] = pack_bf2(fmaf(v[2*ks].x,   inv, nmi), fmaf(v[2*ks].y,   inv, nmi));
    cv.u[1] = pack_bf2(fmaf(v[2*ks].z,   inv, nmi), fmaf(v[2*ks].w,   inv, nmi));
    cv.u[2] = pack_bf2(fmaf(v[2*ks+1].x, inv, nmi), fmaf(v[2*ks+1].y, inv, nmi));
    cv.u[3] = pack_bf2(fmaf(v[2*ks+1].z, inv, nmi), fmaf(v[2*ks+1].w, inv, nmi));
    af[ks] = cv.s;
  }
}

// Pass 0a: cast+transpose weights to bf16 W^T[n][k], folding ln_g into rows.
__global__ void prep_weights(const float* __restrict__ ln_g,
                             const float* __restrict__ Wq,
                             const float* __restrict__ Wkv,
                             const float* __restrict__ Wo,
                             short* __restrict__ wqT, short* __restrict__ wkvT,
                             short* __restrict__ woT) {
  int t = blockIdx.x * 256 + threadIdx.x;
  if (t < 16384) {                       // WqT[n*128+k] = Wq[k][n]*g[k]
    int n = t >> 7, k = t & 127;
    wqT[t] = (short)f2bf_bits(Wq[k * 128 + n] * ln_g[k]);
  } else if (t < 49152) {                // WkvT[n*128+k] = Wkv[k][n]*g[k]
    int u = t - 16384; int n = u >> 7, k = u & 127;
    wkvT[u] = (short)f2bf_bits(Wkv[k * 256 + n] * ln_g[k]);
  } else if (t < 65536) {                // WoT[n*128+k] = Wo[k][n]
    int u = t - 49152; int n = u >> 7, k = u & 127;
    woT[u] = (short)f2bf_bits(Wo[k * 128 + n]);
  }
}

// Pass 0b: fold ln_b into additive biases: bq = ln_b @ Wq, bkv = ln_b @ Wkv.
__global__ void prep_bias(const float* __restrict__ ln_b,
                          const float* __restrict__ Wq,
                          const float* __restrict__ Wkv,
                          float* __restrict__ bq, float* __restrict__ bkv) {
  int t = blockIdx.x * 256 + threadIdx.x;
  if (t < 128) {
    float s = 0.f;
    for (int k = 0; k < 128; ++k) s = fmaf(ln_b[k], Wq[k * 128 + t], s);
    bq[t] = s;
  } else if (t < 384) {
    int n = t - 128;
    float s = 0.f;
    for (int k = 0; k < 128; ++k) s = fmaf(ln_b[k], Wkv[k * 256 + n], s);
    bkv[n] = s;
  }
}

// One block = 16 points; wave w = head w. LN fused into A-frag register loads
// (y never touches LDS). Only 2 barriers per block (around Os epilogue).
__global__ __launch_bounds__(256) void fused_ca(
    const float* __restrict__ x, const float* __restrict__ y,
    const short* __restrict__ wqT, const short* __restrict__ wkvT,
    const short* __restrict__ woT, const float* __restrict__ bq,
    const float* __restrict__ bkv, const float* __restrict__ bo,
    float* __restrict__ out) {
  __shared__ short Os[16 * RSTR];      // attention outputs (bf16)
  __shared__ float Qs[16 * QSTR];      // q (f32); cols [w*32,w*32+32) wave-private

  const int tid  = threadIdx.x;
  const int w    = tid >> 6;           // wave id = head id
  const int lane = tid & 63;
  const int l16  = lane & 15;
  const int quad = lane >> 4;
  const long gbase = (long)blockIdx.x * 16;

  // ---- register-cache Wkv B-frags: col-tiles (k0,k1,v0,v1) x 4 k-steps ----
  short8 wf[4][4];
  float  bkv_l[4];
#pragma unroll
  for (int ct = 0; ct < 4; ++ct) {
    int n0 = (ct < 2) ? (w * 32 + ct * 16) : (128 + w * 32 + (ct - 2) * 16);
#pragma unroll
    for (int ks = 0; ks < 4; ++ks)
      wf[ct][ks] = *reinterpret_cast<const short8*>(
          wkvT + (n0 + l16) * 128 + ks * 32 + quad * 8);
    bkv_l[ct] = bkv[n0 + l16];
  }

  // ---- Q GEMM: fused-LN x rows (A row = point = l16), wave-private cols ----
  {
    short8 af[4];
    ln_load_frag(x + (gbase + l16) * 128 + quad * 8, af);
#pragma unroll
    for (int t = 0; t < 2; ++t) {
      floatx4 acc = {0.f, 0.f, 0.f, 0.f};
      int n0 = w * 32 + t * 16;
#pragma unroll
      for (int ks = 0; ks < 4; ++ks) {
        short8 bf = *reinterpret_cast<const short8*>(
            wqT + (n0 + l16) * 128 + ks * 32 + quad * 8);
        acc = __builtin_amdgcn_mfma_f32_16x16x32_bf16(af[ks], bf, acc, 0, 0, 0);
      }
      float qb = bq[n0 + l16];
#pragma unroll
      for (int r = 0; r < 4; ++r)
        Qs[(quad * 4 + r) * QSTR + n0 + l16] = acc[r] + qb;  // row = point
    }
  }
  // no barrier: wave w only ever reads its own cols back (same-wave LDS).

  // ---- main loop: 16 points, barrier-free ----
  for (int p = 0; p < 16; ++p) {
    short8 af[4];
    ln_load_frag(y + ((gbase + p) * 16 + l16) * 128 + quad * 8, af);
    floatx4 acc[4];
#pragma unroll
    for (int ct = 0; ct < 4; ++ct) {
      acc[ct] = {0.f, 0.f, 0.f, 0.f};
#pragma unroll
      for (int ks = 0; ks < 4; ++ks)
        acc[ct] = __builtin_amdgcn_mfma_f32_16x16x32_bf16(af[ks], wf[ct][ks],
                                                          acc[ct], 0, 0, 0);
    }
    // k/v with folded ln_b bias; C-layout: row i = quad*4+r, col = w*32(+16)+l16
    float k0[4], k1[4], v0[4], v1[4];
#pragma unroll
    for (int r = 0; r < 4; ++r) {
      k0[r] = acc[0][r] + bkv_l[0];
      k1[r] = acc[1][r] + bkv_l[1];
      v0[r] = acc[2][r] + bkv_l[2];
      v1[r] = acc[3][r] + bkv_l[3];
    }
    float qv0 = Qs[p * QSTR + w * 32 + l16];
    float qv1 = Qs[p * QSTR + w * 32 + 16 + l16];
    float part[4];
#pragma unroll
    for (int r = 0; r < 4; ++r)
      part[r] = fmaf(qv0, k0[r], qv1 * k1[r]);
#pragma unroll
    for (int m = 1; m <= 8; m <<= 1) {        // reduce over 16 d-lanes (DPP)
#pragma unroll
      for (int r = 0; r < 4; ++r) part[r] += __shfl_xor(part[r], m, 64);
    }
    // softmax without max-sub: |dots*SCALE| bounded ~4, exp safe
    float e[4], s = 0.f;
#pragma unroll
    for (int r = 0; r < 4; ++r) { e[r] = __expf(part[r] * SCALE); s += e[r]; }
    float o0 = 0.f, o1 = 0.f;
#pragma unroll
    for (int r = 0; r < 4; ++r) { o0 = fmaf(e[r], v0[r], o0); o1 = fmaf(e[r], v1[r], o1); }
    s  += __shfl_xor(s, 16, 64);  s  += __shfl_xor(s, 32, 64);
    o0 += __shfl_xor(o0, 16, 64); o0 += __shfl_xor(o0, 32, 64);
    o1 += __shfl_xor(o1, 16, 64); o1 += __shfl_xor(o1, 32, 64);
    float rs = 1.0f / s;
    if (quad == 0) {
      Os[p * RSTR + w * 32 + l16]      = (short)f2bf_bits(o0 * rs);
      Os[p * RSTR + w * 32 + 16 + l16] = (short)f2bf_bits(o1 * rs);
    }
  }
  __syncthreads();

  // ---- output GEMM: Os[16 pts,128] @ Wo + bo + x -> out ----
  {
    short8 af[4];
#pragma unroll
    for (int ks = 0; ks < 4; ++ks)
      af[ks] = *reinterpret_cast<const short8*>(Os + l16 * RSTR + ks * 32 + quad * 8);
#pragma unroll
    for (int t = 0; t < 2; ++t) {
      floatx4 acc = {0.f, 0.f, 0.f, 0.f};
      int n0 = w * 32 + t * 16;
#pragma unroll
      for (int ks = 0; ks < 4; ++ks) {
        short8 bf = *reinterpret_cast<const short8*>(
            woT + (n0 + l16) * 128 + ks * 32 + quad * 8);
        acc = __builtin_amdgcn_mfma_f32_16x16x32_bf16(af[ks], bf, acc, 0, 0, 0);
      }
      float bias = bo[n0 + l16];
#pragma unroll
      for (int r = 0; r < 4; ++r) {
        long g = gbase + quad * 4 + r;   // C row = point index
        out[g * 128 + n0 + l16] = acc[r] + bias + x[g * 128 + n0 + l16];
      }
    }
  }
}

extern "C" void kernel_launch(void* const* d_in, const int* in_sizes, int n_in,
                              void* d_out, int out_size, void* d_ws, size_t ws_size,
                              hipStream_t stream) {
  const float* x    = (const float*)d_in[0];
  const float* y    = (const float*)d_in[1];
  const float* ln_g = (const float*)d_in[2];
  const float* ln_b = (const float*)d_in[3];
  const float* Wq   = (const float*)d_in[4];
  const float* Wkv  = (const float*)d_in[5];
  const float* Wo   = (const float*)d_in[6];
  const float* bo   = (const float*)d_in[7];
  float* out = (float*)d_out;

  short* wqT  = (short*)d_ws;                         // 16384 bf16
  short* wkvT = wqT + 16384;                          // 32768 bf16
  short* woT  = wkvT + 32768;                         // 16384 bf16
  float* bq   = (float*)((char*)d_ws + 131072);       // 128 f32
  float* bkv  = bq + 128;                             // 256 f32

  prep_weights<<<256, 256, 0, stream>>>(ln_g, Wq, Wkv, Wo, wqT, wkvT, woT);
  prep_bias<<<2, 256, 0, stream>>>(ln_b, Wq, Wkv, bq, bkv);
  fused_ca<<<4096, 256, 0, stream>>>(x, y, wqT, wkvT, woT, bq, bkv, bo, out);
}